// Round 16
// baseline (299.529 us; speedup 1.0000x reference)
//
#include <hip/hip_runtime.h>
#include <stdint.h>

typedef unsigned short u16;
using short8 = __attribute__((ext_vector_type(8))) short;
using f32x4  = __attribute__((ext_vector_type(4))) float;
using f32x16 = __attribute__((ext_vector_type(16))) float;
using u16x4  = __attribute__((ext_vector_type(4))) unsigned short;
using u32x4  = __attribute__((ext_vector_type(4))) unsigned int;

#define B_   4
#define S_   2048
#define H_   16
#define D_   64
#define NOUT 1024

__device__ __forceinline__ u16 f2b(float f) {
    union { float f; unsigned u; } v; v.f = f;
    unsigned u = v.u;
    unsigned r = (u + 0x7fffu + ((u >> 16) & 1u)) >> 16;
    return (u16)r;
}

__device__ __forceinline__ float b2f(u16 x) {
    union { unsigned u; float f; } v; v.u = ((unsigned)x) << 16; return v.f;
}

__device__ __forceinline__ void gload_lds16(const void* g, void* l) {
    auto gp = (__attribute__((address_space(1))) void*)(uintptr_t)g;
    auto lp = (__attribute__((address_space(3))) void*)(unsigned)(uintptr_t)l;
    __builtin_amdgcn_global_load_lds(gp, lp, 16, 0, 0);
}

__device__ __forceinline__ unsigned cvtpk(float lo, float hi) {
    unsigned r;
    asm("v_cvt_pk_bf16_f32 %0, %1, %2" : "=v"(r) : "v"(lo), "v"(hi));
    return r;
}

// swap high 32 lanes of a with low 32 lanes of b (VALU cross-lane, no LDS pipe)
__device__ __forceinline__ void pswap(unsigned& a, unsigned& b) {
    asm volatile("v_permlane32_swap_b32 %0, %1" : "+v"(a), "+v"(b));
}

// load 8 consecutive f32 and convert to bf16 short8
__device__ __forceinline__ short8 ld8f2b(const float* p) {
    float4 a = *(const float4*)p;
    float4 b = *(const float4*)(p + 4);
    u16 t[8] = {f2b(a.x), f2b(a.y), f2b(a.z), f2b(a.w),
                f2b(b.x), f2b(b.y), f2b(b.z), f2b(b.w)};
    return *(short8*)t;
}

__device__ __forceinline__ f32x16 zero16() {
    f32x16 z;
#pragma unroll
    for (int i = 0; i < 16; ++i) z[i] = 0.f;
    return z;
}

// read a short8 from a row-XOR-swizzled LDS tile (rows of 128B)
__device__ __forceinline__ short8 ldsrd(const u16* base, int row, int colb) {
    return *(const short8*)((const char*)base + row * 128 + (colb ^ ((row & 7) << 4)));
}

// ---------------- f32 -> bf16 convert ----------------
__global__ __launch_bounds__(256) void k_f2b(const float* __restrict__ in,
                                             u16* __restrict__ out, int n) {
    int idx = (blockIdx.x * 256 + threadIdx.x) * 4;
    int stride = gridDim.x * 256 * 4;
    for (; idx < n; idx += stride) {
        float4 v = *(const float4*)&in[idx];
        u16x4 o;
        o.x = f2b(v.x); o.y = f2b(v.y); o.z = f2b(v.z); o.w = f2b(v.w);
        *(u16x4*)&out[idx] = o;
    }
}

// ---------------- Q/K projection GEMM: C = X @ W^T + b, head-major bf16 out ----------------
// BK=64, XOR-swizzled LDS (rows of 128B), 2 barriers per 64-K step.
// Q output pre-scaled by 0.125*log2(e) so attention can use exp2 directly.
__global__ __launch_bounds__(256) void k_gemm_qk(
    const u16* __restrict__ Xq, const u16* __restrict__ Xk,
    const u16* __restrict__ Wqb, const u16* __restrict__ Wkb,
    const float* __restrict__ bq, const float* __restrict__ bk,
    u16* __restrict__ Qh, u16* __restrict__ Kh)
{
    const u16* X     = blockIdx.z ? Xk  : Xq;
    const u16* W     = blockIdx.z ? Wkb : Wqb;
    const float* bias = blockIdx.z ? bk : bq;
    u16* out         = blockIdx.z ? Kh  : Qh;
    const float osc  = blockIdx.z ? 1.0f : 0.18033688011112042f; // 0.125 * log2(e)

    __shared__ __attribute__((aligned(16))) u16 Al[128 * 64];
    __shared__ __attribute__((aligned(16))) u16 Bl[128 * 64];

    const int tid  = threadIdx.x;
    const int wave = tid >> 6, lane = tid & 63;
    const int lrow = lane & 15, kgrp = lane >> 4;
    const int wr = wave >> 1, wc = wave & 1;
    const int m0 = blockIdx.y * 128, n0 = blockIdx.x * 128;

    const f32x4 zero = {0.f, 0.f, 0.f, 0.f};
    f32x4 acc[4][4];
#pragma unroll
    for (int m = 0; m < 4; ++m)
#pragma unroll
        for (int n = 0; n < 4; ++n) acc[m][n] = zero;

    const int srow = lane >> 3;              // row within 8-row slice
    const int slot = (lane & 7) ^ srow;      // inverse-swizzled source slot

    for (int kt = 0; kt < NOUT; kt += 64) {
#pragma unroll
        for (int r = 0; r < 4; ++r) {
            const int row = r * 32 + wave * 8 + srow;
            gload_lds16(&X[(size_t)(m0 + row) * NOUT + kt + slot * 8],
                        &Al[(r * 32 + wave * 8) * 64]);
            gload_lds16(&W[(size_t)(n0 + row) * NOUT + kt + slot * 8],
                        &Bl[(r * 32 + wave * 8) * 64]);
        }
        __syncthreads();
#pragma unroll
        for (int kk = 0; kk < 2; ++kk) {
            short8 af[4], bfr[4];
#pragma unroll
            for (int m = 0; m < 4; ++m)
                af[m] = ldsrd(Al, wr * 64 + m * 16 + lrow, kk * 64 + kgrp * 16);
#pragma unroll
            for (int n = 0; n < 4; ++n)
                bfr[n] = ldsrd(Bl, wc * 64 + n * 16 + lrow, kk * 64 + kgrp * 16);
#pragma unroll
            for (int m = 0; m < 4; ++m)
#pragma unroll
                for (int n = 0; n < 4; ++n)
                    acc[m][n] = __builtin_amdgcn_mfma_f32_16x16x32_bf16(af[m], bfr[n], acc[m][n], 0, 0, 0);
        }
        __syncthreads();
    }

#pragma unroll
    for (int m = 0; m < 4; ++m) {
        const int gmb = m0 + wr * 64 + m * 16 + kgrp * 4;
#pragma unroll
        for (int n = 0; n < 4; ++n) {
            const int gn = n0 + wc * 64 + n * 16 + lrow;
            const float bb = bias[gn];
            const int h = gn >> 6, d = gn & 63;
#pragma unroll
            for (int j = 0; j < 4; ++j) {
                const int gm = gmb + j;
                const int bat = gm >> 11, ss = gm & 2047;
                out[(((size_t)bat * H_ + h) * S_ + ss) * D_ + d] = f2b((acc[m][n][j] + bb) * osc);
            }
        }
    }
}

// ---------------- fused V linear + transpose: Vtg[bh][e][s] = sum_d vals[b,s,h*64+d]*Wv[e,d] + bv[e] ----------------
__global__ __launch_bounds__(256) void k_vprojT(
    const float* __restrict__ vals, const float* __restrict__ Wv,
    const float* __restrict__ bv, u16* __restrict__ Vtg)
{
    __shared__ u16 OT[64 * 260];   // [e][token], stride 260 u16 (bank-spread, 8B-aligned)

    const int tid = threadIdx.x, wave = tid >> 6, lane = tid & 63;
    const int lrow = lane & 15, kgrp = lane >> 4;
    const int bh = blockIdx.y, b = bh >> 4, h = bh & 15;
    const int s0 = blockIdx.x * 256;

    // A-fragments: Wv[e][d], row = e = m*16+lrow, k = d = kc*32 + kgrp*8
    short8 af[4][2];
#pragma unroll
    for (int m = 0; m < 4; ++m)
#pragma unroll
        for (int kc = 0; kc < 2; ++kc)
            af[m][kc] = ld8f2b(&Wv[(m * 16 + lrow) * 64 + kc * 32 + kgrp * 8]);

    const f32x4 zero = {0.f, 0.f, 0.f, 0.f};
    f32x4 acc[4][4];
#pragma unroll
    for (int m = 0; m < 4; ++m)
#pragma unroll
        for (int nt = 0; nt < 4; ++nt) acc[m][nt] = zero;

    const float* vb = &vals[(size_t)(b * S_ + s0 + wave * 64) * NOUT + h * 64];
#pragma unroll
    for (int nt = 0; nt < 4; ++nt) {
#pragma unroll
        for (int kc = 0; kc < 2; ++kc) {
            short8 bf = ld8f2b(vb + (size_t)(nt * 16 + lrow) * NOUT + kc * 32 + kgrp * 8);
#pragma unroll
            for (int m = 0; m < 4; ++m)
                acc[m][nt] = __builtin_amdgcn_mfma_f32_16x16x32_bf16(af[m][kc], bf, acc[m][nt], 0, 0, 0);
        }
    }

    // bias + transpose-stage: OT[e][tok]
#pragma unroll
    for (int m = 0; m < 4; ++m) {
        const int e0 = m * 16 + kgrp * 4;
#pragma unroll
        for (int j = 0; j < 4; ++j) {
            const float bb = bv[e0 + j];
#pragma unroll
            for (int nt = 0; nt < 4; ++nt)
                OT[(e0 + j) * 260 + wave * 64 + nt * 16 + lrow] = f2b(acc[m][nt][j] + bb);
        }
    }
    __syncthreads();

    // coalesced write-out: thread (e = tid>>2, tq = tid&3) writes 64 tokens = 8 x short8
    const int e = tid >> 2, tq = tid & 3;
    const size_t gb = (size_t)bh * (S_ * D_) + (size_t)e * S_ + s0 + tq * 64;
#pragma unroll
    for (int i = 0; i < 8; ++i) {
        const int o = e * 260 + tq * 64 + i * 8;
        uint2 lo = *(const uint2*)&OT[o];        // tokens +0..3
        uint2 hi = *(const uint2*)&OT[o + 4];    // tokens +4..7
        u32x4 w = {lo.x, lo.y, hi.x, hi.y};
        *(short8*)&Vtg[gb + i * 8] = __builtin_bit_cast(short8, w);
    }
}

// ---------------- Flash attention: 8 waves x 32 q-rows (256-row tile), 32x32x16 MFMA ----------------
// Subtile-pipelined: both 64-key subtiles' QK^T MFMAs issue back-to-back after the
// barrier, then exp/pack(s0) | PV(s0) | exp/pack(s1) | PV(s1) — the scheduler can
// interleave the independent VALU of s1 into PV(s0)'s MFMA shadow.
__global__ __launch_bounds__(512, 4) void k_attn(
    const u16* __restrict__ Qh, const u16* __restrict__ Kh,
    const u16* __restrict__ Vtg, u16* __restrict__ Og)
{
    // 64KB: K dbuf 2x(2x8KB subtiles) [0,32KB) | V^T dbuf 2x(2x8KB) [32,64KB)
    __shared__ __attribute__((aligned(16))) u16 lds[32768];

    const int tid = threadIdx.x, wave = tid >> 6, lane = tid & 63;
    const int l31 = lane & 31, hi = lane >> 5;

    // XCD swizzle: w -> (xcd = w&7, slot = w>>3, 64 slots/XCD); bh = xcd*8 + slot/8; qt = slot&7.
    const int w = blockIdx.y * 8 + blockIdx.x;
    const int xcd = w & 7, slot = w >> 3;
    const int bh = (xcd << 3) | (slot >> 3);
    const int qt = slot & 7;
    const int b = bh >> 4, h = bh & 15;
    const int q0 = qt * 256;
    const size_t kvbase = (size_t)bh * (S_ * D_);

    // Q fragments (B-operand): B[col=q=l31][k = hi*8+e = d], 4 chunks of k=16
    short8 qf[4];
    {
        const size_t qrow = kvbase + (size_t)(q0 + wave * 32 + l31) * 64;
#pragma unroll
        for (int kc = 0; kc < 4; ++kc)
            qf[kc] = *(const short8*)&Qh[qrow + kc * 16 + hi * 8];
    }

    // all-ones bf16 A-fragment for the l-sum MFMA
    short8 ones;
#pragma unroll
    for (int i = 0; i < 8; ++i) ones[i] = (short)0x3F80;

    f32x16 O0 = zero16(), O1 = zero16(), lacc = zero16();

    // 8 waves: each stages one 8-row slice per 64-key sub-tile (2 K + 2 V loads per wave)
    auto stage = [&](int buf, int kt) {
        const int row = wave * 8 + (lane >> 3);
        const int slt = (lane & 7) ^ (row & 7);          // inverse-swizzled source slot
#pragma unroll
        for (int r = 0; r < 2; ++r) {
            gload_lds16(&Kh [kvbase + (size_t)(kt + r * 64 + row) * 64 + slt * 8],
                        &lds[buf * 8192 + r * 4096 + wave * 512]);
            gload_lds16(&Vtg[kvbase + (size_t)row * S_ + kt + r * 64 + slt * 8],
                        &lds[16384 + buf * 8192 + r * 4096 + wave * 512]);
        }
    };

    // exp2 in place + pack to B-operand fragments (pf[c] elem j = P[key = c*16 + hi*8 + j])
    auto expack = [&](f32x16& s0, f32x16& s1, short8* pf) {
#pragma unroll
        for (int i = 0; i < 16; ++i) { s0[i] = exp2f(s0[i]); s1[i] = exp2f(s1[i]); }
#pragma unroll
        for (int c = 0; c < 4; ++c) {
            const int be = 8 * (c & 1);
            unsigned A0, A1, B0, B1;
            if (c < 2) {
                A0 = cvtpk(s0[be + 0], s0[be + 1]); A1 = cvtpk(s0[be + 2], s0[be + 3]);
                B0 = cvtpk(s0[be + 4], s0[be + 5]); B1 = cvtpk(s0[be + 6], s0[be + 7]);
            } else {
                A0 = cvtpk(s1[be + 0], s1[be + 1]); A1 = cvtpk(s1[be + 2], s1[be + 3]);
                B0 = cvtpk(s1[be + 4], s1[be + 5]); B1 = cvtpk(s1[be + 6], s1[be + 7]);
            }
            pswap(A0, B0);   // A0 -> keys {be*2+0,1 | +8,9}, B0 -> keys {be*2+4,5 | +12,13}
            pswap(A1, B1);
            u32x4 w2 = {A0, A1, B0, B1};
            pf[c] = __builtin_bit_cast(short8, w2);
        }
    };

    stage(0, 0);
    asm volatile("s_waitcnt vmcnt(0)" ::: "memory");
    __syncthreads();

    for (int t = 0; t < S_ / 128; ++t) {
        const int buf = t & 1;
        if (t + 1 < S_ / 128) stage(buf ^ 1, (t + 1) * 128);
        const u16* Kb0 = &lds[buf * 8192];
        const u16* Kb1 = &lds[buf * 8192 + 4096];
        const u16* Vb0 = &lds[16384 + buf * 8192];
        const u16* Vb1 = &lds[16384 + buf * 8192 + 4096];

        // QK^T for BOTH subtiles back-to-back (16 MFMA fill the matrix pipe)
        f32x16 sA0 = zero16(), sA1 = zero16(), sB0 = zero16(), sB1 = zero16();
        __builtin_amdgcn_s_setprio(1);
#pragma unroll
        for (int kc = 0; kc < 4; ++kc) {
            sA0 = __builtin_amdgcn_mfma_f32_32x32x16_bf16(ldsrd(Kb0, l31,      kc * 32 + hi * 16), qf[kc], sA0, 0, 0, 0);
            sA1 = __builtin_amdgcn_mfma_f32_32x32x16_bf16(ldsrd(Kb0, 32 + l31, kc * 32 + hi * 16), qf[kc], sA1, 0, 0, 0);
        }
#pragma unroll
        for (int kc = 0; kc < 4; ++kc) {
            sB0 = __builtin_amdgcn_mfma_f32_32x32x16_bf16(ldsrd(Kb1, l31,      kc * 32 + hi * 16), qf[kc], sB0, 0, 0, 0);
            sB1 = __builtin_amdgcn_mfma_f32_32x32x16_bf16(ldsrd(Kb1, 32 + l31, kc * 32 + hi * 16), qf[kc], sB1, 0, 0, 0);
        }
        __builtin_amdgcn_s_setprio(0);

        // s0 softmax+PV, s1 exp/pack interleavable into PV(s0)'s shadow
        short8 pfA[4], pfB[4];
        expack(sA0, sA1, pfA);
        __builtin_amdgcn_s_setprio(1);
#pragma unroll
        for (int c = 0; c < 4; ++c) {
            lacc = __builtin_amdgcn_mfma_f32_32x32x16_bf16(ones, pfA[c], lacc, 0, 0, 0);
            O0 = __builtin_amdgcn_mfma_f32_32x32x16_bf16(ldsrd(Vb0, l31,      c * 32 + hi * 16), pfA[c], O0, 0, 0, 0);
            O1 = __builtin_amdgcn_mfma_f32_32x32x16_bf16(ldsrd(Vb0, 32 + l31, c * 32 + hi * 16), pfA[c], O1, 0, 0, 0);
        }
        __builtin_amdgcn_s_setprio(0);
        expack(sB0, sB1, pfB);
        __builtin_amdgcn_s_setprio(1);
#pragma unroll
        for (int c = 0; c < 4; ++c) {
            lacc = __builtin_amdgcn_mfma_f32_32x32x16_bf16(ones, pfB[c], lacc, 0, 0, 0);
            O0 = __builtin_amdgcn_mfma_f32_32x32x16_bf16(ldsrd(Vb1, l31,      c * 32 + hi * 16), pfB[c], O0, 0, 0, 0);
            O1 = __builtin_amdgcn_mfma_f32_32x32x16_bf16(ldsrd(Vb1, 32 + l31, c * 32 + hi * 16), pfB[c], O1, 0, 0, 0);
        }
        __builtin_amdgcn_s_setprio(0);

        asm volatile("s_waitcnt vmcnt(0)" ::: "memory");
        __syncthreads();
    }

    const float rl = 1.0f / lacc[0];   // MFMA k-dim spans both hi halves -> full l
    O0 *= rl;
    O1 *= rl;

    // stage O (bf16) into swizzled LDS rows [q 0..255][d 0..63] (32 KB, reuses K space)
    const int r256 = wave * 32 + l31;
    const unsigned swz = (unsigned)((r256 & 7) << 4);
#pragma unroll
    for (int dt = 0; dt < 2; ++dt) {
#pragma unroll
        for (int rr = 0; rr < 4; ++rr) {
            const f32x16& Ot = dt ? O1 : O0;
            unsigned w0 = cvtpk(Ot[4 * rr + 0], Ot[4 * rr + 1]);
            unsigned w1 = cvtpk(Ot[4 * rr + 2], Ot[4 * rr + 3]);
            const int colb = (dt * 64 + rr * 16 + hi * 8) ^ swz;
            *(uint2*)((char*)lds + r256 * 128 + colb) = make_uint2(w0, w1);
        }
    }
    __syncthreads();

    // each thread: (row = tid>>1, half = tid&1) -> 32 d-elements = 4 x short8
    const int orow = tid >> 1, ohalf = tid & 1;
    const size_t gbase = ((size_t)(b * S_ + q0 + orow) * H_ + h) * D_ + ohalf * 32;
#pragma unroll
    for (int j = 0; j < 4; ++j) {
        const int colb = (ohalf * 64 + j * 16) ^ ((orow & 7) << 4);
        short8 v = *(const short8*)((const char*)lds + orow * 128 + colb);
        *(short8*)&Og[gbase + j * 8] = v;
    }
}

// ---------------- head-sum: osum_bf16[token][d] = sum_h O[token][h][d] ----------------
__global__ __launch_bounds__(256) void k_hsum(const u16* __restrict__ O,
                                              u16* __restrict__ osum) {
    const int tk = blockIdx.x * 32 + (threadIdx.x >> 3);
    const int d8 = (threadIdx.x & 7) * 8;
    float a[8] = {0.f, 0.f, 0.f, 0.f, 0.f, 0.f, 0.f, 0.f};
    const u16* p = &O[(size_t)tk * (H_ * D_) + d8];
#pragma unroll
    for (int h = 0; h < H_; ++h) {
        short8 v = *(const short8*)&p[h * 64];
#pragma unroll
        for (int i = 0; i < 8; ++i) a[i] += b2f((u16)v[i]);
    }
    u16 ob[8];
#pragma unroll
    for (int i = 0; i < 8; ++i) ob[i] = f2b(a[i]);
    *(short8*)&osum[(size_t)tk * 64 + d8] = *(short8*)&ob[0];
}

// ---------------- final projection GEMM: out[m][n] = sum_k osum[m][k]*Wo[n][k] + bo[n] ----------------
__global__ __launch_bounds__(256) void k_oproj2(
    const u16* __restrict__ A, const u16* __restrict__ Bt,
    const float* __restrict__ bo, float* __restrict__ out)
{
    __shared__ __attribute__((aligned(16))) u16 Al[128 * 64];
    __shared__ __attribute__((aligned(16))) u16 Bl[128 * 64];

    const int tid  = threadIdx.x;
    const int wave = tid >> 6, lane = tid & 63;
    const int lrow = lane & 15, kgrp = lane >> 4;
    const int wr = wave >> 1, wc = wave & 1;
    const int m0 = blockIdx.y * 128, n0 = blockIdx.x * 128;

    const int arow = tid >> 3;
    const int acol = (tid & 7) * 8;

#pragma unroll
    for (int r = 0; r < 4; ++r) {
        gload_lds16(&A [(size_t)(m0 + r * 32 + arow) * 64 + acol], &Al[(r * 32 + wave * 8) * 64]);
        gload_lds16(&Bt[(size_t)(n0 + r * 32 + arow) * 64 + acol], &Bl[(r * 32 + wave * 8) * 64]);
    }
    __syncthreads();

    const f32x4 zero = {0.f, 0.f, 0.f, 0.f};
    f32x4 acc[4][4];
#pragma unroll
    for (int m = 0; m < 4; ++m)
#pragma unroll
        for (int n = 0; n < 4; ++n) acc[m][n] = zero;

#pragma unroll
    for (int ks = 0; ks < 2; ++ks) {
        short8 af[4], bfr[4];
#pragma unroll
        for (int m = 0; m < 4; ++m)
            af[m] = *(const short8*)&Al[(wr * 64 + m * 16 + lrow) * 64 + ks * 32 + kgrp * 8];
#pragma unroll
        for (int n = 0; n < 4; ++n)
            bfr[n] = *(const short8*)&Bl[(wc * 64 + n * 16 + lrow) * 64 + ks * 32 + kgrp * 8];
#pragma unroll
        for (int m = 0; m < 4; ++m)
#pragma unroll
            for (int n = 0; n < 4; ++n)
                acc[m][n] = __builtin_amdgcn_mfma_f32_16x16x32_bf16(af[m], bfr[n], acc[m][n], 0, 0, 0);
    }

#pragma unroll
    for (int m = 0; m < 4; ++m) {
        const int gm = m0 + wr * 64 + m * 16 + kgrp * 4;
#pragma unroll
        for (int n = 0; n < 4; ++n) {
            const int gn = n0 + wc * 64 + n * 16 + lrow;
            const float bb = bo[gn];
#pragma unroll
            for (int j = 0; j < 4; ++j)
                out[(size_t)(gm + j) * NOUT + gn] = acc[m][n][j] + bb;
        }
    }
}

extern "C" void kernel_launch(void* const* d_in, const int* in_sizes, int n_in,
                              void* d_out, int out_size, void* d_ws, size_t ws_size,
                              hipStream_t stream) {
    const float* queries = (const float*)d_in[0];
    const float* keys    = (const float*)d_in[1];
    const float* values  = (const float*)d_in[2];
    const float* Wq = (const float*)d_in[3];
    const float* bq = (const float*)d_in[4];
    const float* Wk = (const float*)d_in[5];
    const float* bk = (const float*)d_in[6];
    const float* Wv = (const float*)d_in[7];
    const float* bv = (const float*)d_in[8];
    const float* Wo = (const float*)d_in[9];
    const float* bo = (const float*)d_in[10];
    float* out = (float*)d_out;

    char* ws = (char*)d_ws;
    u16* qbf   = (u16*)(ws + 0);                       // 16 MiB (dead after gemm)
    u16* kbf   = (u16*)(ws + (16ull << 20));           // 16 MiB (dead after gemm)
    u16* Oar   = (u16*)(ws + 0);                       // 16 MiB bf16, aliases qbf
    u16* Vtg   = (u16*)(ws + (16ull << 20));           // 16 MiB, aliases kbf (written after gemm)
    u16* wqb   = (u16*)(ws + (32ull << 20));           // 2 MiB
    u16* wkb   = (u16*)(ws + (34ull << 20));           // 2 MiB
    u16* Qh    = (u16*)(ws + (36ull << 20));           // 16 MiB
    u16* Kh    = (u16*)(ws + (52ull << 20));           // 16 MiB (dead after attn)
    u16* wob   = (u16*)(ws + (52ull << 20));           // aliases Kh
    u16* osum  = (u16*)(ws + (54ull << 20));           // aliases Kh+2MiB

    const int NTOK = B_ * S_;                          // 8192
    k_f2b<<<2048, 256, 0, stream>>>(queries, qbf, NTOK * NOUT);
    k_f2b<<<2048, 256, 0, stream>>>(keys,    kbf, NTOK * NOUT);
    k_f2b<<<512,  256, 0, stream>>>(Wq, wqb, NOUT * NOUT);
    k_f2b<<<512,  256, 0, stream>>>(Wk, wkb, NOUT * NOUT);

    k_gemm_qk<<<dim3(NOUT / 128, NTOK / 128, 2), 256, 0, stream>>>(
        qbf, kbf, wqb, wkb, bq, bk, Qh, Kh);

    k_vprojT<<<dim3(S_ / 256, B_ * H_), 256, 0, stream>>>(values, Wv, bv, Vtg);

    // 512 blocks (8 qt x 64 bh) x 512 threads
    k_attn<<<dim3(8, 64), 512, 0, stream>>>(Qh, Kh, Vtg, Oar);

    k_f2b<<<64, 256, 0, stream>>>(Wo, wob, NOUT * D_);
    k_hsum<<<NTOK / 32, 256, 0, stream>>>(Oar, osum);
    k_oproj2<<<dim3(NOUT / 128, NTOK / 128), 256, 0, stream>>>(osum, wob, bo, out);
}

// Round 17
// 201.420 us; speedup vs baseline: 1.4871x; 1.4871x over previous
//
#include <hip/hip_runtime.h>
#include <stdint.h>

typedef unsigned short u16;
using short8 = __attribute__((ext_vector_type(8))) short;
using f32x4  = __attribute__((ext_vector_type(4))) float;
using f32x16 = __attribute__((ext_vector_type(16))) float;
using u16x4  = __attribute__((ext_vector_type(4))) unsigned short;
using u32x4  = __attribute__((ext_vector_type(4))) unsigned int;

#define B_   4
#define S_   2048
#define H_   16
#define D_   64
#define NOUT 1024

__device__ __forceinline__ u16 f2b(float f) {
    union { float f; unsigned u; } v; v.f = f;
    unsigned u = v.u;
    unsigned r = (u + 0x7fffu + ((u >> 16) & 1u)) >> 16;
    return (u16)r;
}

__device__ __forceinline__ float b2f(u16 x) {
    union { unsigned u; float f; } v; v.u = ((unsigned)x) << 16; return v.f;
}

__device__ __forceinline__ void gload_lds16(const void* g, void* l) {
    auto gp = (__attribute__((address_space(1))) void*)(uintptr_t)g;
    auto lp = (__attribute__((address_space(3))) void*)(unsigned)(uintptr_t)l;
    __builtin_amdgcn_global_load_lds(gp, lp, 16, 0, 0);
}

__device__ __forceinline__ unsigned cvtpk(float lo, float hi) {
    unsigned r;
    asm("v_cvt_pk_bf16_f32 %0, %1, %2" : "=v"(r) : "v"(lo), "v"(hi));
    return r;
}

// swap high 32 lanes of a with low 32 lanes of b (VALU cross-lane, no LDS pipe)
__device__ __forceinline__ void pswap(unsigned& a, unsigned& b) {
    asm volatile("v_permlane32_swap_b32 %0, %1" : "+v"(a), "+v"(b));
}

// load 8 consecutive f32 and convert to bf16 short8
__device__ __forceinline__ short8 ld8f2b(const float* p) {
    float4 a = *(const float4*)p;
    float4 b = *(const float4*)(p + 4);
    u16 t[8] = {f2b(a.x), f2b(a.y), f2b(a.z), f2b(a.w),
                f2b(b.x), f2b(b.y), f2b(b.z), f2b(b.w)};
    return *(short8*)t;
}

__device__ __forceinline__ f32x16 zero16() {
    f32x16 z;
#pragma unroll
    for (int i = 0; i < 16; ++i) z[i] = 0.f;
    return z;
}

// read a short8 from a row-XOR-swizzled LDS tile (rows of 128B)
__device__ __forceinline__ short8 ldsrd(const u16* base, int row, int colb) {
    return *(const short8*)((const char*)base + row * 128 + (colb ^ ((row & 7) << 4)));
}

// ---------------- f32 -> bf16 convert ----------------
__global__ __launch_bounds__(256) void k_f2b(const float* __restrict__ in,
                                             u16* __restrict__ out, int n) {
    int idx = (blockIdx.x * 256 + threadIdx.x) * 4;
    int stride = gridDim.x * 256 * 4;
    for (; idx < n; idx += stride) {
        float4 v = *(const float4*)&in[idx];
        u16x4 o;
        o.x = f2b(v.x); o.y = f2b(v.y); o.z = f2b(v.z); o.w = f2b(v.w);
        *(u16x4*)&out[idx] = o;
    }
}

// ---------------- Q/K projection GEMM: C = X @ W^T + b, head-major bf16 out ----------------
// BK=64, XOR-swizzled LDS (rows of 128B), 2 barriers per 64-K step.
// Q output pre-scaled by 0.125*log2(e) so attention can use exp2 directly.
__global__ __launch_bounds__(256) void k_gemm_qk(
    const u16* __restrict__ Xq, const u16* __restrict__ Xk,
    const u16* __restrict__ Wqb, const u16* __restrict__ Wkb,
    const float* __restrict__ bq, const float* __restrict__ bk,
    u16* __restrict__ Qh, u16* __restrict__ Kh)
{
    const u16* X     = blockIdx.z ? Xk  : Xq;
    const u16* W     = blockIdx.z ? Wkb : Wqb;
    const float* bias = blockIdx.z ? bk : bq;
    u16* out         = blockIdx.z ? Kh  : Qh;
    const float osc  = blockIdx.z ? 1.0f : 0.18033688011112042f; // 0.125 * log2(e)

    __shared__ __attribute__((aligned(16))) u16 Al[128 * 64];
    __shared__ __attribute__((aligned(16))) u16 Bl[128 * 64];

    const int tid  = threadIdx.x;
    const int wave = tid >> 6, lane = tid & 63;
    const int lrow = lane & 15, kgrp = lane >> 4;
    const int wr = wave >> 1, wc = wave & 1;
    const int m0 = blockIdx.y * 128, n0 = blockIdx.x * 128;

    const f32x4 zero = {0.f, 0.f, 0.f, 0.f};
    f32x4 acc[4][4];
#pragma unroll
    for (int m = 0; m < 4; ++m)
#pragma unroll
        for (int n = 0; n < 4; ++n) acc[m][n] = zero;

    const int srow = lane >> 3;              // row within 8-row slice
    const int slot = (lane & 7) ^ srow;      // inverse-swizzled source slot

    for (int kt = 0; kt < NOUT; kt += 64) {
#pragma unroll
        for (int r = 0; r < 4; ++r) {
            const int row = r * 32 + wave * 8 + srow;
            gload_lds16(&X[(size_t)(m0 + row) * NOUT + kt + slot * 8],
                        &Al[(r * 32 + wave * 8) * 64]);
            gload_lds16(&W[(size_t)(n0 + row) * NOUT + kt + slot * 8],
                        &Bl[(r * 32 + wave * 8) * 64]);
        }
        __syncthreads();
#pragma unroll
        for (int kk = 0; kk < 2; ++kk) {
            short8 af[4], bfr[4];
#pragma unroll
            for (int m = 0; m < 4; ++m)
                af[m] = ldsrd(Al, wr * 64 + m * 16 + lrow, kk * 64 + kgrp * 16);
#pragma unroll
            for (int n = 0; n < 4; ++n)
                bfr[n] = ldsrd(Bl, wc * 64 + n * 16 + lrow, kk * 64 + kgrp * 16);
#pragma unroll
            for (int m = 0; m < 4; ++m)
#pragma unroll
                for (int n = 0; n < 4; ++n)
                    acc[m][n] = __builtin_amdgcn_mfma_f32_16x16x32_bf16(af[m], bfr[n], acc[m][n], 0, 0, 0);
        }
        __syncthreads();
    }

#pragma unroll
    for (int m = 0; m < 4; ++m) {
        const int gmb = m0 + wr * 64 + m * 16 + kgrp * 4;
#pragma unroll
        for (int n = 0; n < 4; ++n) {
            const int gn = n0 + wc * 64 + n * 16 + lrow;
            const float bb = bias[gn];
            const int h = gn >> 6, d = gn & 63;
#pragma unroll
            for (int j = 0; j < 4; ++j) {
                const int gm = gmb + j;
                const int bat = gm >> 11, ss = gm & 2047;
                out[(((size_t)bat * H_ + h) * S_ + ss) * D_ + d] = f2b((acc[m][n][j] + bb) * osc);
            }
        }
    }
}

// ---------------- fused V linear + transpose: Vtg[bh][e][s] = sum_d vals[b,s,h*64+d]*Wv[e,d] + bv[e] ----------------
__global__ __launch_bounds__(256) void k_vprojT(
    const float* __restrict__ vals, const float* __restrict__ Wv,
    const float* __restrict__ bv, u16* __restrict__ Vtg)
{
    __shared__ u16 OT[64 * 260];   // [e][token], stride 260 u16 (bank-spread, 8B-aligned)

    const int tid = threadIdx.x, wave = tid >> 6, lane = tid & 63;
    const int lrow = lane & 15, kgrp = lane >> 4;
    const int bh = blockIdx.y, b = bh >> 4, h = bh & 15;
    const int s0 = blockIdx.x * 256;

    // A-fragments: Wv[e][d], row = e = m*16+lrow, k = d = kc*32 + kgrp*8
    short8 af[4][2];
#pragma unroll
    for (int m = 0; m < 4; ++m)
#pragma unroll
        for (int kc = 0; kc < 2; ++kc)
            af[m][kc] = ld8f2b(&Wv[(m * 16 + lrow) * 64 + kc * 32 + kgrp * 8]);

    const f32x4 zero = {0.f, 0.f, 0.f, 0.f};
    f32x4 acc[4][4];
#pragma unroll
    for (int m = 0; m < 4; ++m)
#pragma unroll
        for (int nt = 0; nt < 4; ++nt) acc[m][nt] = zero;

    const float* vb = &vals[(size_t)(b * S_ + s0 + wave * 64) * NOUT + h * 64];
#pragma unroll
    for (int nt = 0; nt < 4; ++nt) {
#pragma unroll
        for (int kc = 0; kc < 2; ++kc) {
            short8 bf = ld8f2b(vb + (size_t)(nt * 16 + lrow) * NOUT + kc * 32 + kgrp * 8);
#pragma unroll
            for (int m = 0; m < 4; ++m)
                acc[m][nt] = __builtin_amdgcn_mfma_f32_16x16x32_bf16(af[m][kc], bf, acc[m][nt], 0, 0, 0);
        }
    }

    // bias + transpose-stage: OT[e][tok]
#pragma unroll
    for (int m = 0; m < 4; ++m) {
        const int e0 = m * 16 + kgrp * 4;
#pragma unroll
        for (int j = 0; j < 4; ++j) {
            const float bb = bv[e0 + j];
#pragma unroll
            for (int nt = 0; nt < 4; ++nt)
                OT[(e0 + j) * 260 + wave * 64 + nt * 16 + lrow] = f2b(acc[m][nt][j] + bb);
        }
    }
    __syncthreads();

    // coalesced write-out: thread (e = tid>>2, tq = tid&3) writes 64 tokens = 8 x short8
    const int e = tid >> 2, tq = tid & 3;
    const size_t gb = (size_t)bh * (S_ * D_) + (size_t)e * S_ + s0 + tq * 64;
#pragma unroll
    for (int i = 0; i < 8; ++i) {
        const int o = e * 260 + tq * 64 + i * 8;
        uint2 lo = *(const uint2*)&OT[o];        // tokens +0..3
        uint2 hi = *(const uint2*)&OT[o + 4];    // tokens +4..7
        u32x4 w = {lo.x, lo.y, hi.x, hi.y};
        *(short8*)&Vtg[gb + i * 8] = __builtin_bit_cast(short8, w);
    }
}

// ---------------- Flash attention: 8 waves x 32 q-rows (256-row tile), 32x32x16 MFMA ----------------
// Scores: mfma(A=K, B=Q) -> S[key][q], q = lane&31 (lane-local).
// Softmax without max subtraction (shift-invariant; scores bounded); exp2 in-place.
// l via ones-row MFMA (C-accumulating, spans both hi halves -> no end shfl).
// 128 keys per barrier (two 64-key sub-tiles, identical read math, offset bases).
__global__ __launch_bounds__(512, 4) void k_attn(
    const u16* __restrict__ Qh, const u16* __restrict__ Kh,
    const u16* __restrict__ Vtg, u16* __restrict__ Og)
{
    // 64KB: K dbuf 2x(2x8KB subtiles) [0,32KB) | V^T dbuf 2x(2x8KB) [32,64KB)
    __shared__ __attribute__((aligned(16))) u16 lds[32768];

    const int tid = threadIdx.x, wave = tid >> 6, lane = tid & 63;
    const int l31 = lane & 31, hi = lane >> 5;

    // XCD swizzle: w -> (xcd = w&7, slot = w>>3, 64 slots/XCD); bh = xcd*8 + slot/8; qt = slot&7.
    const int w = blockIdx.y * 8 + blockIdx.x;
    const int xcd = w & 7, slot = w >> 3;
    const int bh = (xcd << 3) | (slot >> 3);
    const int qt = slot & 7;
    const int b = bh >> 4, h = bh & 15;
    const int q0 = qt * 256;
    const size_t kvbase = (size_t)bh * (S_ * D_);

    // Q fragments (B-operand): B[col=q=l31][k = hi*8+e = d], 4 chunks of k=16
    short8 qf[4];
    {
        const size_t qrow = kvbase + (size_t)(q0 + wave * 32 + l31) * 64;
#pragma unroll
        for (int kc = 0; kc < 4; ++kc)
            qf[kc] = *(const short8*)&Qh[qrow + kc * 16 + hi * 8];
    }

    // all-ones bf16 A-fragment for the l-sum MFMA
    short8 ones;
#pragma unroll
    for (int i = 0; i < 8; ++i) ones[i] = (short)0x3F80;

    f32x16 O0 = zero16(), O1 = zero16(), lacc = zero16();

    // 8 waves: each stages one 8-row slice per 64-key sub-tile (2 K + 2 V loads per wave)
    auto stage = [&](int buf, int kt) {
        const int row = wave * 8 + (lane >> 3);
        const int slt = (lane & 7) ^ (row & 7);          // inverse-swizzled source slot
#pragma unroll
        for (int r = 0; r < 2; ++r) {
            gload_lds16(&Kh [kvbase + (size_t)(kt + r * 64 + row) * 64 + slt * 8],
                        &lds[buf * 8192 + r * 4096 + wave * 512]);
            gload_lds16(&Vtg[kvbase + (size_t)row * S_ + kt + r * 64 + slt * 8],
                        &lds[16384 + buf * 8192 + r * 4096 + wave * 512]);
        }
    };

    stage(0, 0);
    asm volatile("s_waitcnt vmcnt(0)" ::: "memory");
    __syncthreads();

    for (int t = 0; t < S_ / 128; ++t) {
        const int buf = t & 1;
        if (t + 1 < S_ / 128) stage(buf ^ 1, (t + 1) * 128);
#pragma unroll
        for (int sub = 0; sub < 2; ++sub) {
            const u16* Kb = &lds[buf * 8192 + sub * 4096];
            const u16* Vb = &lds[16384 + buf * 8192 + sub * 4096];

            // S[key][q] over 64 keys (two 32-key C tiles)
            f32x16 s0 = zero16(), s1 = zero16();
            __builtin_amdgcn_s_setprio(1);
#pragma unroll
            for (int kc = 0; kc < 4; ++kc) {
                s0 = __builtin_amdgcn_mfma_f32_32x32x16_bf16(ldsrd(Kb, l31,      kc * 32 + hi * 16), qf[kc], s0, 0, 0, 0);
                s1 = __builtin_amdgcn_mfma_f32_32x32x16_bf16(ldsrd(Kb, 32 + l31, kc * 32 + hi * 16), qf[kc], s1, 0, 0, 0);
            }
            __builtin_amdgcn_s_setprio(0);

            // P = exp2(S) in-place (shift-invariant softmax; scores bounded)
#pragma unroll
            for (int i = 0; i < 16; ++i) { s0[i] = exp2f(s0[i]); s1[i] = exp2f(s1[i]); }

            // P fragments: pf[c] elem j = P[key = c*16 + hi*8 + j].
            short8 pf[4];
#pragma unroll
            for (int c = 0; c < 4; ++c) {
                const int be = 8 * (c & 1);
                unsigned A0, A1, B0, B1;
                if (c < 2) {
                    A0 = cvtpk(s0[be + 0], s0[be + 1]); A1 = cvtpk(s0[be + 2], s0[be + 3]);
                    B0 = cvtpk(s0[be + 4], s0[be + 5]); B1 = cvtpk(s0[be + 6], s0[be + 7]);
                } else {
                    A0 = cvtpk(s1[be + 0], s1[be + 1]); A1 = cvtpk(s1[be + 2], s1[be + 3]);
                    B0 = cvtpk(s1[be + 4], s1[be + 5]); B1 = cvtpk(s1[be + 6], s1[be + 7]);
                }
                pswap(A0, B0);   // A0 -> keys {be*2+0,1 | +8,9}, B0 -> keys {be*2+4,5 | +12,13}
                pswap(A1, B1);
                u32x4 w2 = {A0, A1, B0, B1};
                pf[c] = __builtin_bit_cast(short8, w2);
            }

            // O[d][q] += V^T x P; l[q] += ones x P (MFMA accumulates the row-sum)
            __builtin_amdgcn_s_setprio(1);
#pragma unroll
            for (int c = 0; c < 4; ++c) {
                lacc = __builtin_amdgcn_mfma_f32_32x32x16_bf16(ones, pf[c], lacc, 0, 0, 0);
                O0 = __builtin_amdgcn_mfma_f32_32x32x16_bf16(ldsrd(Vb, l31,      c * 32 + hi * 16), pf[c], O0, 0, 0, 0);
                O1 = __builtin_amdgcn_mfma_f32_32x32x16_bf16(ldsrd(Vb, 32 + l31, c * 32 + hi * 16), pf[c], O1, 0, 0, 0);
            }
            __builtin_amdgcn_s_setprio(0);
        }

        asm volatile("s_waitcnt vmcnt(0)" ::: "memory");
        __syncthreads();
    }

    const float rl = 1.0f / lacc[0];   // MFMA k-dim spans both hi halves -> full l
    O0 *= rl;
    O1 *= rl;

    // stage O (bf16) into swizzled LDS rows [q 0..255][d 0..63] (32 KB, reuses K space)
    const int r256 = wave * 32 + l31;
    const unsigned swz = (unsigned)((r256 & 7) << 4);
#pragma unroll
    for (int dt = 0; dt < 2; ++dt) {
#pragma unroll
        for (int rr = 0; rr < 4; ++rr) {
            const f32x16& Ot = dt ? O1 : O0;
            unsigned w0 = cvtpk(Ot[4 * rr + 0], Ot[4 * rr + 1]);
            unsigned w1 = cvtpk(Ot[4 * rr + 2], Ot[4 * rr + 3]);
            const int colb = (dt * 64 + rr * 16 + hi * 8) ^ swz;
            *(uint2*)((char*)lds + r256 * 128 + colb) = make_uint2(w0, w1);
        }
    }
    __syncthreads();

    // each thread: (row = tid>>1, half = tid&1) -> 32 d-elements = 4 x short8
    const int orow = tid >> 1, ohalf = tid & 1;
    const size_t gbase = ((size_t)(b * S_ + q0 + orow) * H_ + h) * D_ + ohalf * 32;
#pragma unroll
    for (int j = 0; j < 4; ++j) {
        const int colb = (ohalf * 64 + j * 16) ^ ((orow & 7) << 4);
        short8 v = *(const short8*)((const char*)lds + orow * 128 + colb);
        *(short8*)&Og[gbase + j * 8] = v;
    }
}

// ---------------- head-sum: osum_bf16[token][d] = sum_h O[token][h][d] ----------------
__global__ __launch_bounds__(256) void k_hsum(const u16* __restrict__ O,
                                              u16* __restrict__ osum) {
    const int tk = blockIdx.x * 32 + (threadIdx.x >> 3);
    const int d8 = (threadIdx.x & 7) * 8;
    float a[8] = {0.f, 0.f, 0.f, 0.f, 0.f, 0.f, 0.f, 0.f};
    const u16* p = &O[(size_t)tk * (H_ * D_) + d8];
#pragma unroll
    for (int h = 0; h < H_; ++h) {
        short8 v = *(const short8*)&p[h * 64];
#pragma unroll
        for (int i = 0; i < 8; ++i) a[i] += b2f((u16)v[i]);
    }
    u16 ob[8];
#pragma unroll
    for (int i = 0; i < 8; ++i) ob[i] = f2b(a[i]);
    *(short8*)&osum[(size_t)tk * 64 + d8] = *(short8*)&ob[0];
}

// ---------------- final projection GEMM: out[m][n] = sum_k osum[m][k]*Wo[n][k] + bo[n] ----------------
__global__ __launch_bounds__(256) void k_oproj2(
    const u16* __restrict__ A, const u16* __restrict__ Bt,
    const float* __restrict__ bo, float* __restrict__ out)
{
    __shared__ __attribute__((aligned(16))) u16 Al[128 * 64];
    __shared__ __attribute__((aligned(16))) u16 Bl[128 * 64];

    const int tid  = threadIdx.x;
    const int wave = tid >> 6, lane = tid & 63;
    const int lrow = lane & 15, kgrp = lane >> 4;
    const int wr = wave >> 1, wc = wave & 1;
    const int m0 = blockIdx.y * 128, n0 = blockIdx.x * 128;

    const int arow = tid >> 3;
    const int acol = (tid & 7) * 8;

#pragma unroll
    for (int r = 0; r < 4; ++r) {
        gload_lds16(&A [(size_t)(m0 + r * 32 + arow) * 64 + acol], &Al[(r * 32 + wave * 8) * 64]);
        gload_lds16(&Bt[(size_t)(n0 + r * 32 + arow) * 64 + acol], &Bl[(r * 32 + wave * 8) * 64]);
    }
    __syncthreads();

    const f32x4 zero = {0.f, 0.f, 0.f, 0.f};
    f32x4 acc[4][4];
#pragma unroll
    for (int m = 0; m < 4; ++m)
#pragma unroll
        for (int n = 0; n < 4; ++n) acc[m][n] = zero;

#pragma unroll
    for (int ks = 0; ks < 2; ++ks) {
        short8 af[4], bfr[4];
#pragma unroll
        for (int m = 0; m < 4; ++m)
            af[m] = *(const short8*)&Al[(wr * 64 + m * 16 + lrow) * 64 + ks * 32 + kgrp * 8];
#pragma unroll
        for (int n = 0; n < 4; ++n)
            bfr[n] = *(const short8*)&Bl[(wc * 64 + n * 16 + lrow) * 64 + ks * 32 + kgrp * 8];
#pragma unroll
        for (int m = 0; m < 4; ++m)
#pragma unroll
            for (int n = 0; n < 4; ++n)
                acc[m][n] = __builtin_amdgcn_mfma_f32_16x16x32_bf16(af[m], bfr[n], acc[m][n], 0, 0, 0);
    }

#pragma unroll
    for (int m = 0; m < 4; ++m) {
        const int gm = m0 + wr * 64 + m * 16 + kgrp * 4;
#pragma unroll
        for (int n = 0; n < 4; ++n) {
            const int gn = n0 + wc * 64 + n * 16 + lrow;
            const float bb = bo[gn];
#pragma unroll
            for (int j = 0; j < 4; ++j)
                out[(size_t)(gm + j) * NOUT + gn] = acc[m][n][j] + bb;
        }
    }
}

extern "C" void kernel_launch(void* const* d_in, const int* in_sizes, int n_in,
                              void* d_out, int out_size, void* d_ws, size_t ws_size,
                              hipStream_t stream) {
    const float* queries = (const float*)d_in[0];
    const float* keys    = (const float*)d_in[1];
    const float* values  = (const float*)d_in[2];
    const float* Wq = (const float*)d_in[3];
    const float* bq = (const float*)d_in[4];
    const float* Wk = (const float*)d_in[5];
    const float* bk = (const float*)d_in[6];
    const float* Wv = (const float*)d_in[7];
    const float* bv = (const float*)d_in[8];
    const float* Wo = (const float*)d_in[9];
    const float* bo = (const float*)d_in[10];
    float* out = (float*)d_out;

    char* ws = (char*)d_ws;
    u16* qbf   = (u16*)(ws + 0);                       // 16 MiB (dead after gemm)
    u16* kbf   = (u16*)(ws + (16ull << 20));           // 16 MiB (dead after gemm)
    u16* Oar   = (u16*)(ws + 0);                       // 16 MiB bf16, aliases qbf
    u16* Vtg   = (u16*)(ws + (16ull << 20));           // 16 MiB, aliases kbf (written after gemm)
    u16* wqb   = (u16*)(ws + (32ull << 20));           // 2 MiB
    u16* wkb   = (u16*)(ws + (34ull << 20));           // 2 MiB
    u16* Qh    = (u16*)(ws + (36ull << 20));           // 16 MiB
    u16* Kh    = (u16*)(ws + (52ull << 20));           // 16 MiB (dead after attn)
    u16* wob   = (u16*)(ws + (52ull << 20));           // aliases Kh
    u16* osum  = (u16*)(ws + (54ull << 20));           // aliases Kh+2MiB

    const int NTOK = B_ * S_;                          // 8192
    k_f2b<<<2048, 256, 0, stream>>>(queries, qbf, NTOK * NOUT);
    k_f2b<<<2048, 256, 0, stream>>>(keys,    kbf, NTOK * NOUT);
    k_f2b<<<512,  256, 0, stream>>>(Wq, wqb, NOUT * NOUT);
    k_f2b<<<512,  256, 0, stream>>>(Wk, wkb, NOUT * NOUT);

    k_gemm_qk<<<dim3(NOUT / 128, NTOK / 128, 2), 256, 0, stream>>>(
        qbf, kbf, wqb, wkb, bq, bk, Qh, Kh);

    k_vprojT<<<dim3(S_ / 256, B_ * H_), 256, 0, stream>>>(values, Wv, bv, Vtg);

    // 512 blocks (8 qt x 64 bh) x 512 threads
    k_attn<<<dim3(8, 64), 512, 0, stream>>>(Qh, Kh, Vtg, Oar);

    k_f2b<<<64, 256, 0, stream>>>(Wo, wob, NOUT * D_);
    k_hsum<<<NTOK / 32, 256, 0, stream>>>(Oar, osum);
    k_oproj2<<<dim3(NOUT / 128, NTOK / 128), 256, 0, stream>>>(osum, wob, bo, out);
}

// Round 18
// 200.844 us; speedup vs baseline: 1.4914x; 1.0029x over previous
//
#include <hip/hip_runtime.h>
#include <stdint.h>

typedef unsigned short u16;
using short8 = __attribute__((ext_vector_type(8))) short;
using f32x4  = __attribute__((ext_vector_type(4))) float;
using f32x16 = __attribute__((ext_vector_type(16))) float;
using u16x4  = __attribute__((ext_vector_type(4))) unsigned short;
using u32x4  = __attribute__((ext_vector_type(4))) unsigned int;

#define B_   4
#define S_   2048
#define H_   16
#define D_   64
#define NOUT 1024

__device__ __forceinline__ u16 f2b(float f) {
    union { float f; unsigned u; } v; v.f = f;
    unsigned u = v.u;
    unsigned r = (u + 0x7fffu + ((u >> 16) & 1u)) >> 16;
    return (u16)r;
}

__device__ __forceinline__ float b2f(u16 x) {
    union { unsigned u; float f; } v; v.u = ((unsigned)x) << 16; return v.f;
}

__device__ __forceinline__ void gload_lds16(const void* g, void* l) {
    auto gp = (__attribute__((address_space(1))) void*)(uintptr_t)g;
    auto lp = (__attribute__((address_space(3))) void*)(unsigned)(uintptr_t)l;
    __builtin_amdgcn_global_load_lds(gp, lp, 16, 0, 0);
}

__device__ __forceinline__ unsigned cvtpk(float lo, float hi) {
    unsigned r;
    asm("v_cvt_pk_bf16_f32 %0, %1, %2" : "=v"(r) : "v"(lo), "v"(hi));
    return r;
}

// swap high 32 lanes of a with low 32 lanes of b (VALU cross-lane, no LDS pipe)
__device__ __forceinline__ void pswap(unsigned& a, unsigned& b) {
    asm volatile("v_permlane32_swap_b32 %0, %1" : "+v"(a), "+v"(b));
}

// load 8 consecutive f32 and convert to bf16 short8
__device__ __forceinline__ short8 ld8f2b(const float* p) {
    float4 a = *(const float4*)p;
    float4 b = *(const float4*)(p + 4);
    u16 t[8] = {f2b(a.x), f2b(a.y), f2b(a.z), f2b(a.w),
                f2b(b.x), f2b(b.y), f2b(b.z), f2b(b.w)};
    return *(short8*)t;
}

__device__ __forceinline__ f32x16 zero16() {
    f32x16 z;
#pragma unroll
    for (int i = 0; i < 16; ++i) z[i] = 0.f;
    return z;
}

// read a short8 from a row-XOR-swizzled LDS tile (rows of 128B)
__device__ __forceinline__ short8 ldsrd(const u16* base, int row, int colb) {
    return *(const short8*)((const char*)base + row * 128 + (colb ^ ((row & 7) << 4)));
}

// ---------------- f32 -> bf16 convert ----------------
__global__ __launch_bounds__(256) void k_f2b(const float* __restrict__ in,
                                             u16* __restrict__ out, int n) {
    int idx = (blockIdx.x * 256 + threadIdx.x) * 4;
    int stride = gridDim.x * 256 * 4;
    for (; idx < n; idx += stride) {
        float4 v = *(const float4*)&in[idx];
        u16x4 o;
        o.x = f2b(v.x); o.y = f2b(v.y); o.z = f2b(v.z); o.w = f2b(v.w);
        *(u16x4*)&out[idx] = o;
    }
}

// ---------------- Q/K projection GEMM: C = X @ W^T + b, head-major bf16 out ----------------
// BK=64, XOR-swizzled LDS, 32x32x16 MFMA (half the instruction count of 16x16x32).
// Fragment reads use the attention-verified ldsrd(row=l31, colb=kc*32+hi*16) pattern;
// C/D layout: col = lane&31, row = (reg&3) + 8*(reg>>2) + 4*(lane>>5).
// Q output pre-scaled by 0.125*log2(e) so attention can use exp2 directly.
__global__ __launch_bounds__(256) void k_gemm_qk(
    const u16* __restrict__ Xq, const u16* __restrict__ Xk,
    const u16* __restrict__ Wqb, const u16* __restrict__ Wkb,
    const float* __restrict__ bq, const float* __restrict__ bk,
    u16* __restrict__ Qh, u16* __restrict__ Kh)
{
    const u16* X     = blockIdx.z ? Xk  : Xq;
    const u16* W     = blockIdx.z ? Wkb : Wqb;
    const float* bias = blockIdx.z ? bk : bq;
    u16* out         = blockIdx.z ? Kh  : Qh;
    const float osc  = blockIdx.z ? 1.0f : 0.18033688011112042f; // 0.125 * log2(e)

    __shared__ __attribute__((aligned(16))) u16 Al[128 * 64];
    __shared__ __attribute__((aligned(16))) u16 Bl[128 * 64];

    const int tid  = threadIdx.x;
    const int wave = tid >> 6, lane = tid & 63;
    const int l31 = lane & 31, hi = lane >> 5;
    const int wr = wave >> 1, wc = wave & 1;
    const int m0 = blockIdx.y * 128, n0 = blockIdx.x * 128;

    f32x16 acc[2][2];
#pragma unroll
    for (int tm = 0; tm < 2; ++tm)
#pragma unroll
        for (int tn = 0; tn < 2; ++tn) acc[tm][tn] = zero16();

    const int srow = lane >> 3;              // row within 8-row slice
    const int slot = (lane & 7) ^ srow;      // inverse-swizzled source slot

    for (int kt = 0; kt < NOUT; kt += 64) {
#pragma unroll
        for (int r = 0; r < 4; ++r) {
            const int row = r * 32 + wave * 8 + srow;
            gload_lds16(&X[(size_t)(m0 + row) * NOUT + kt + slot * 8],
                        &Al[(r * 32 + wave * 8) * 64]);
            gload_lds16(&W[(size_t)(n0 + row) * NOUT + kt + slot * 8],
                        &Bl[(r * 32 + wave * 8) * 64]);
        }
        __syncthreads();
#pragma unroll
        for (int kc = 0; kc < 4; ++kc) {
            short8 a0 = ldsrd(Al, wr * 64 + l31,      kc * 32 + hi * 16);
            short8 a1 = ldsrd(Al, wr * 64 + 32 + l31, kc * 32 + hi * 16);
            short8 b0 = ldsrd(Bl, wc * 64 + l31,      kc * 32 + hi * 16);
            short8 b1 = ldsrd(Bl, wc * 64 + 32 + l31, kc * 32 + hi * 16);
            acc[0][0] = __builtin_amdgcn_mfma_f32_32x32x16_bf16(a0, b0, acc[0][0], 0, 0, 0);
            acc[0][1] = __builtin_amdgcn_mfma_f32_32x32x16_bf16(a0, b1, acc[0][1], 0, 0, 0);
            acc[1][0] = __builtin_amdgcn_mfma_f32_32x32x16_bf16(a1, b0, acc[1][0], 0, 0, 0);
            acc[1][1] = __builtin_amdgcn_mfma_f32_32x32x16_bf16(a1, b1, acc[1][1], 0, 0, 0);
        }
        __syncthreads();
    }

#pragma unroll
    for (int tm = 0; tm < 2; ++tm) {
#pragma unroll
        for (int tn = 0; tn < 2; ++tn) {
            const int gn = n0 + wc * 64 + tn * 32 + l31;
            const float bb = bias[gn];
            const int h = gn >> 6, d = gn & 63;
#pragma unroll
            for (int j = 0; j < 16; ++j) {
                const int crow = (j & 3) + 8 * (j >> 2) + 4 * hi;
                const int gm = m0 + wr * 64 + tm * 32 + crow;
                const int bat = gm >> 11, ss = gm & 2047;
                out[(((size_t)bat * H_ + h) * S_ + ss) * D_ + d] =
                    f2b((acc[tm][tn][j] + bb) * osc);
            }
        }
    }
}

// ---------------- fused V linear + transpose: Vtg[bh][e][s] = sum_d vals[b,s,h*64+d]*Wv[e,d] + bv[e] ----------------
__global__ __launch_bounds__(256) void k_vprojT(
    const float* __restrict__ vals, const float* __restrict__ Wv,
    const float* __restrict__ bv, u16* __restrict__ Vtg)
{
    __shared__ u16 OT[64 * 260];   // [e][token], stride 260 u16 (bank-spread, 8B-aligned)

    const int tid = threadIdx.x, wave = tid >> 6, lane = tid & 63;
    const int lrow = lane & 15, kgrp = lane >> 4;
    const int bh = blockIdx.y, b = bh >> 4, h = bh & 15;
    const int s0 = blockIdx.x * 256;

    // A-fragments: Wv[e][d], row = e = m*16+lrow, k = d = kc*32 + kgrp*8
    short8 af[4][2];
#pragma unroll
    for (int m = 0; m < 4; ++m)
#pragma unroll
        for (int kc = 0; kc < 2; ++kc)
            af[m][kc] = ld8f2b(&Wv[(m * 16 + lrow) * 64 + kc * 32 + kgrp * 8]);

    const f32x4 zero = {0.f, 0.f, 0.f, 0.f};
    f32x4 acc[4][4];
#pragma unroll
    for (int m = 0; m < 4; ++m)
#pragma unroll
        for (int nt = 0; nt < 4; ++nt) acc[m][nt] = zero;

    const float* vb = &vals[(size_t)(b * S_ + s0 + wave * 64) * NOUT + h * 64];
#pragma unroll
    for (int nt = 0; nt < 4; ++nt) {
#pragma unroll
        for (int kc = 0; kc < 2; ++kc) {
            short8 bf = ld8f2b(vb + (size_t)(nt * 16 + lrow) * NOUT + kc * 32 + kgrp * 8);
#pragma unroll
            for (int m = 0; m < 4; ++m)
                acc[m][nt] = __builtin_amdgcn_mfma_f32_16x16x32_bf16(af[m][kc], bf, acc[m][nt], 0, 0, 0);
        }
    }

    // bias + transpose-stage: OT[e][tok]
#pragma unroll
    for (int m = 0; m < 4; ++m) {
        const int e0 = m * 16 + kgrp * 4;
#pragma unroll
        for (int j = 0; j < 4; ++j) {
            const float bb = bv[e0 + j];
#pragma unroll
            for (int nt = 0; nt < 4; ++nt)
                OT[(e0 + j) * 260 + wave * 64 + nt * 16 + lrow] = f2b(acc[m][nt][j] + bb);
        }
    }
    __syncthreads();

    // coalesced write-out: thread (e = tid>>2, tq = tid&3) writes 64 tokens = 8 x short8
    const int e = tid >> 2, tq = tid & 3;
    const size_t gb = (size_t)bh * (S_ * D_) + (size_t)e * S_ + s0 + tq * 64;
#pragma unroll
    for (int i = 0; i < 8; ++i) {
        const int o = e * 260 + tq * 64 + i * 8;
        uint2 lo = *(const uint2*)&OT[o];        // tokens +0..3
        uint2 hi = *(const uint2*)&OT[o + 4];    // tokens +4..7
        u32x4 w = {lo.x, lo.y, hi.x, hi.y};
        *(short8*)&Vtg[gb + i * 8] = __builtin_bit_cast(short8, w);
    }
}

// ---------------- Flash attention: 8 waves x 32 q-rows (256-row tile), 32x32x16 MFMA ----------------
// Scores: mfma(A=K, B=Q) -> S[key][q], q = lane&31 (lane-local).
// Softmax without max subtraction (shift-invariant; scores bounded); exp2 in-place.
// l via ones-row MFMA (C-accumulating, spans both hi halves -> no end shfl).
// 128 keys per barrier (two 64-key sub-tiles, identical read math, offset bases).
__global__ __launch_bounds__(512, 4) void k_attn(
    const u16* __restrict__ Qh, const u16* __restrict__ Kh,
    const u16* __restrict__ Vtg, u16* __restrict__ Og)
{
    // 64KB: K dbuf 2x(2x8KB subtiles) [0,32KB) | V^T dbuf 2x(2x8KB) [32,64KB)
    __shared__ __attribute__((aligned(16))) u16 lds[32768];

    const int tid = threadIdx.x, wave = tid >> 6, lane = tid & 63;
    const int l31 = lane & 31, hi = lane >> 5;

    // XCD swizzle: w -> (xcd = w&7, slot = w>>3, 64 slots/XCD); bh = xcd*8 + slot/8; qt = slot&7.
    const int w = blockIdx.y * 8 + blockIdx.x;
    const int xcd = w & 7, slot = w >> 3;
    const int bh = (xcd << 3) | (slot >> 3);
    const int qt = slot & 7;
    const int b = bh >> 4, h = bh & 15;
    const int q0 = qt * 256;
    const size_t kvbase = (size_t)bh * (S_ * D_);

    // Q fragments (B-operand): B[col=q=l31][k = hi*8+e = d], 4 chunks of k=16
    short8 qf[4];
    {
        const size_t qrow = kvbase + (size_t)(q0 + wave * 32 + l31) * 64;
#pragma unroll
        for (int kc = 0; kc < 4; ++kc)
            qf[kc] = *(const short8*)&Qh[qrow + kc * 16 + hi * 8];
    }

    // all-ones bf16 A-fragment for the l-sum MFMA
    short8 ones;
#pragma unroll
    for (int i = 0; i < 8; ++i) ones[i] = (short)0x3F80;

    f32x16 O0 = zero16(), O1 = zero16(), lacc = zero16();

    // 8 waves: each stages one 8-row slice per 64-key sub-tile (2 K + 2 V loads per wave)
    auto stage = [&](int buf, int kt) {
        const int row = wave * 8 + (lane >> 3);
        const int slt = (lane & 7) ^ (row & 7);          // inverse-swizzled source slot
#pragma unroll
        for (int r = 0; r < 2; ++r) {
            gload_lds16(&Kh [kvbase + (size_t)(kt + r * 64 + row) * 64 + slt * 8],
                        &lds[buf * 8192 + r * 4096 + wave * 512]);
            gload_lds16(&Vtg[kvbase + (size_t)row * S_ + kt + r * 64 + slt * 8],
                        &lds[16384 + buf * 8192 + r * 4096 + wave * 512]);
        }
    };

    stage(0, 0);
    asm volatile("s_waitcnt vmcnt(0)" ::: "memory");
    __syncthreads();

    for (int t = 0; t < S_ / 128; ++t) {
        const int buf = t & 1;
        if (t + 1 < S_ / 128) stage(buf ^ 1, (t + 1) * 128);
#pragma unroll
        for (int sub = 0; sub < 2; ++sub) {
            const u16* Kb = &lds[buf * 8192 + sub * 4096];
            const u16* Vb = &lds[16384 + buf * 8192 + sub * 4096];

            // S[key][q] over 64 keys (two 32-key C tiles)
            f32x16 s0 = zero16(), s1 = zero16();
            __builtin_amdgcn_s_setprio(1);
#pragma unroll
            for (int kc = 0; kc < 4; ++kc) {
                s0 = __builtin_amdgcn_mfma_f32_32x32x16_bf16(ldsrd(Kb, l31,      kc * 32 + hi * 16), qf[kc], s0, 0, 0, 0);
                s1 = __builtin_amdgcn_mfma_f32_32x32x16_bf16(ldsrd(Kb, 32 + l31, kc * 32 + hi * 16), qf[kc], s1, 0, 0, 0);
            }
            __builtin_amdgcn_s_setprio(0);

            // P = exp2(S) in-place (shift-invariant softmax; scores bounded)
#pragma unroll
            for (int i = 0; i < 16; ++i) { s0[i] = exp2f(s0[i]); s1[i] = exp2f(s1[i]); }

            // P fragments: pf[c] elem j = P[key = c*16 + hi*8 + j].
            short8 pf[4];
#pragma unroll
            for (int c = 0; c < 4; ++c) {
                const int be = 8 * (c & 1);
                unsigned A0, A1, B0, B1;
                if (c < 2) {
                    A0 = cvtpk(s0[be + 0], s0[be + 1]); A1 = cvtpk(s0[be + 2], s0[be + 3]);
                    B0 = cvtpk(s0[be + 4], s0[be + 5]); B1 = cvtpk(s0[be + 6], s0[be + 7]);
                } else {
                    A0 = cvtpk(s1[be + 0], s1[be + 1]); A1 = cvtpk(s1[be + 2], s1[be + 3]);
                    B0 = cvtpk(s1[be + 4], s1[be + 5]); B1 = cvtpk(s1[be + 6], s1[be + 7]);
                }
                pswap(A0, B0);   // A0 -> keys {be*2+0,1 | +8,9}, B0 -> keys {be*2+4,5 | +12,13}
                pswap(A1, B1);
                u32x4 w2 = {A0, A1, B0, B1};
                pf[c] = __builtin_bit_cast(short8, w2);
            }

            // O[d][q] += V^T x P; l[q] += ones x P (MFMA accumulates the row-sum)
            __builtin_amdgcn_s_setprio(1);
#pragma unroll
            for (int c = 0; c < 4; ++c) {
                lacc = __builtin_amdgcn_mfma_f32_32x32x16_bf16(ones, pf[c], lacc, 0, 0, 0);
                O0 = __builtin_amdgcn_mfma_f32_32x32x16_bf16(ldsrd(Vb, l31,      c * 32 + hi * 16), pf[c], O0, 0, 0, 0);
                O1 = __builtin_amdgcn_mfma_f32_32x32x16_bf16(ldsrd(Vb, 32 + l31, c * 32 + hi * 16), pf[c], O1, 0, 0, 0);
            }
            __builtin_amdgcn_s_setprio(0);
        }

        asm volatile("s_waitcnt vmcnt(0)" ::: "memory");
        __syncthreads();
    }

    const float rl = 1.0f / lacc[0];   // MFMA k-dim spans both hi halves -> full l
    O0 *= rl;
    O1 *= rl;

    // stage O (bf16) into swizzled LDS rows [q 0..255][d 0..63] (32 KB, reuses K space)
    const int r256 = wave * 32 + l31;
    const unsigned swz = (unsigned)((r256 & 7) << 4);
#pragma unroll
    for (int dt = 0; dt < 2; ++dt) {
#pragma unroll
        for (int rr = 0; rr < 4; ++rr) {
            const f32x16& Ot = dt ? O1 : O0;
            unsigned w0 = cvtpk(Ot[4 * rr + 0], Ot[4 * rr + 1]);
            unsigned w1 = cvtpk(Ot[4 * rr + 2], Ot[4 * rr + 3]);
            const int colb = (dt * 64 + rr * 16 + hi * 8) ^ swz;
            *(uint2*)((char*)lds + r256 * 128 + colb) = make_uint2(w0, w1);
        }
    }
    __syncthreads();

    // each thread: (row = tid>>1, half = tid&1) -> 32 d-elements = 4 x short8
    const int orow = tid >> 1, ohalf = tid & 1;
    const size_t gbase = ((size_t)(b * S_ + q0 + orow) * H_ + h) * D_ + ohalf * 32;
#pragma unroll
    for (int j = 0; j < 4; ++j) {
        const int colb = (ohalf * 64 + j * 16) ^ ((orow & 7) << 4);
        short8 v = *(const short8*)((const char*)lds + orow * 128 + colb);
        *(short8*)&Og[gbase + j * 8] = v;
    }
}

// ---------------- head-sum: osum_bf16[token][d] = sum_h O[token][h][d] ----------------
__global__ __launch_bounds__(256) void k_hsum(const u16* __restrict__ O,
                                              u16* __restrict__ osum) {
    const int tk = blockIdx.x * 32 + (threadIdx.x >> 3);
    const int d8 = (threadIdx.x & 7) * 8;
    float a[8] = {0.f, 0.f, 0.f, 0.f, 0.f, 0.f, 0.f, 0.f};
    const u16* p = &O[(size_t)tk * (H_ * D_) + d8];
#pragma unroll
    for (int h = 0; h < H_; ++h) {
        short8 v = *(const short8*)&p[h * 64];
#pragma unroll
        for (int i = 0; i < 8; ++i) a[i] += b2f((u16)v[i]);
    }
    u16 ob[8];
#pragma unroll
    for (int i = 0; i < 8; ++i) ob[i] = f2b(a[i]);
    *(short8*)&osum[(size_t)tk * 64 + d8] = *(short8*)&ob[0];
}

// ---------------- final projection GEMM: out[m][n] = sum_k osum[m][k]*Wo[n][k] + bo[n] ----------------
__global__ __launch_bounds__(256) void k_oproj2(
    const u16* __restrict__ A, const u16* __restrict__ Bt,
    const float* __restrict__ bo, float* __restrict__ out)
{
    __shared__ __attribute__((aligned(16))) u16 Al[128 * 64];
    __shared__ __attribute__((aligned(16))) u16 Bl[128 * 64];

    const int tid  = threadIdx.x;
    const int wave = tid >> 6, lane = tid & 63;
    const int lrow = lane & 15, kgrp = lane >> 4;
    const int wr = wave >> 1, wc = wave & 1;
    const int m0 = blockIdx.y * 128, n0 = blockIdx.x * 128;

    const int arow = tid >> 3;
    const int acol = (tid & 7) * 8;

#pragma unroll
    for (int r = 0; r < 4; ++r) {
        gload_lds16(&A [(size_t)(m0 + r * 32 + arow) * 64 + acol], &Al[(r * 32 + wave * 8) * 64]);
        gload_lds16(&Bt[(size_t)(n0 + r * 32 + arow) * 64 + acol], &Bl[(r * 32 + wave * 8) * 64]);
    }
    __syncthreads();

    const f32x4 zero = {0.f, 0.f, 0.f, 0.f};
    f32x4 acc[4][4];
#pragma unroll
    for (int m = 0; m < 4; ++m)
#pragma unroll
        for (int n = 0; n < 4; ++n) acc[m][n] = zero;

#pragma unroll
    for (int ks = 0; ks < 2; ++ks) {
        short8 af[4], bfr[4];
#pragma unroll
        for (int m = 0; m < 4; ++m)
            af[m] = *(const short8*)&Al[(wr * 64 + m * 16 + lrow) * 64 + ks * 32 + kgrp * 8];
#pragma unroll
        for (int n = 0; n < 4; ++n)
            bfr[n] = *(const short8*)&Bl[(wc * 64 + n * 16 + lrow) * 64 + ks * 32 + kgrp * 8];
#pragma unroll
        for (int m = 0; m < 4; ++m)
#pragma unroll
            for (int n = 0; n < 4; ++n)
                acc[m][n] = __builtin_amdgcn_mfma_f32_16x16x32_bf16(af[m], bfr[n], acc[m][n], 0, 0, 0);
    }

#pragma unroll
    for (int m = 0; m < 4; ++m) {
        const int gm = m0 + wr * 64 + m * 16 + kgrp * 4;
#pragma unroll
        for (int n = 0; n < 4; ++n) {
            const int gn = n0 + wc * 64 + n * 16 + lrow;
            const float bb = bo[gn];
#pragma unroll
            for (int j = 0; j < 4; ++j)
                out[(size_t)(gm + j) * NOUT + gn] = acc[m][n][j] + bb;
        }
    }
}

extern "C" void kernel_launch(void* const* d_in, const int* in_sizes, int n_in,
                              void* d_out, int out_size, void* d_ws, size_t ws_size,
                              hipStream_t stream) {
    const float* queries = (const float*)d_in[0];
    const float* keys    = (const float*)d_in[1];
    const float* values  = (const float*)d_in[2];
    const float* Wq = (const float*)d_in[3];
    const float* bq = (const float*)d_in[4];
    const float* Wk = (const float*)d_in[5];
    const float* bk = (const float*)d_in[6];
    const float* Wv = (const float*)d_in[7];
    const float* bv = (const float*)d_in[8];
    const float* Wo = (const float*)d_in[9];
    const float* bo = (const float*)d_in[10];
    float* out = (float*)d_out;

    char* ws = (char*)d_ws;
    u16* qbf   = (u16*)(ws + 0);                       // 16 MiB (dead after gemm)
    u16* kbf   = (u16*)(ws + (16ull << 20));           // 16 MiB (dead after gemm)
    u16* Oar   = (u16*)(ws + 0);                       // 16 MiB bf16, aliases qbf
    u16* Vtg   = (u16*)(ws + (16ull << 20));           // 16 MiB, aliases kbf (written after gemm)
    u16* wqb   = (u16*)(ws + (32ull << 20));           // 2 MiB
    u16* wkb   = (u16*)(ws + (34ull << 20));           // 2 MiB
    u16* Qh    = (u16*)(ws + (36ull << 20));           // 16 MiB
    u16* Kh    = (u16*)(ws + (52ull << 20));           // 16 MiB (dead after attn)
    u16* wob   = (u16*)(ws + (52ull << 20));           // aliases Kh
    u16* osum  = (u16*)(ws + (54ull << 20));           // aliases Kh+2MiB

    const int NTOK = B_ * S_;                          // 8192
    k_f2b<<<2048, 256, 0, stream>>>(queries, qbf, NTOK * NOUT);
    k_f2b<<<2048, 256, 0, stream>>>(keys,    kbf, NTOK * NOUT);
    k_f2b<<<512,  256, 0, stream>>>(Wq, wqb, NOUT * NOUT);
    k_f2b<<<512,  256, 0, stream>>>(Wk, wkb, NOUT * NOUT);

    k_gemm_qk<<<dim3(NOUT / 128, NTOK / 128, 2), 256, 0, stream>>>(
        qbf, kbf, wqb, wkb, bq, bk, Qh, Kh);

    k_vprojT<<<dim3(S_ / 256, B_ * H_), 256, 0, stream>>>(values, Wv, bv, Vtg);

    // 512 blocks (8 qt x 64 bh) x 512 threads
    k_attn<<<dim3(8, 64), 512, 0, stream>>>(Qh, Kh, Vtg, Oar);

    k_f2b<<<64, 256, 0, stream>>>(Wo, wob, NOUT * D_);
    k_hsum<<<NTOK / 32, 256, 0, stream>>>(Oar, osum);
    k_oproj2<<<dim3(NOUT / 128, NTOK / 128), 256, 0, stream>>>(osum, wob, bo, out);
}